// Round 3
// baseline (233834.814 us; speedup 1.0000x reference)
//
#include <hip/hip_runtime.h>
#include <hip/hip_bf16.h>

typedef __hip_bfloat16 bf16;

#define NSTEP 1024
#define BATCH 64
#define HID   512
#define GRID  256
#define NTHR  256
#define STRIP 160
#define KC    32
#define PAD   34

// ---- workspace layout (bytes) ----
#define OFF_BAR   0u
#define OFF_FLAG  64u
#define OFF_HG    256u
#define OFF_CG    131328u
#define OFF_GALL  262400u
#define OFF_UCAT  2883840u
#define OFF_WA    23855360u
#define OFF_WM    24903936u
#define OFF_WX    25166080u
#define OFF_BM    25362688u
#define OFF_BX    25370880u
#define OFF_BA    25403648u
#define OFF_YT    25405696u
#define OFF_XT    33794304u
// end ~40085760 (~38.2 MB)

struct RawIn {
  const void *Y, *x[8];
  const void *W_i,*U_i,*b_i, *W_f,*U_f,*b_f, *W_c,*U_c,*b_c, *W_o,*U_o,*b_o;
  const void *W_ix,*U_ix,*b_ix, *W_cx,*U_cx,*b_cx, *W_a,*b_a;
  float *Ucat,*Wa,*Wm,*Wx,*Bm,*Bx,*Ba,*Yt,*Xt;
  const unsigned *flag;
};

struct Params {
  const float *Ucat,*Wa,*Wm,*Wx,*Bm,*Bx,*Ba,*Yt,*Xt;
  float *Hg,*Cg,*Gall;
  unsigned *bar;
  const unsigned *flag;
  void *out;
};

// ---------------- dtype probe -------------------------------------------------
// bf16 small-magnitude data: every uint16's exponent field (bits 7..14) sits in
// a narrow band. fp32 data read as uint16: even indices are random mantissa
// bits -> exponent field uniform. Count plausible halves over 64.
__global__ void k_detect(const unsigned short* __restrict__ p, unsigned* flag) {
  if (blockIdx.x == 0 && threadIdx.x == 0) {
    int cnt = 0;
    for (int i = 0; i < 64; ++i) {
      unsigned e = (p[i] >> 7) & 0xFF;
      cnt += (e >= 0x60 && e <= 0x7C) || (p[i] & 0x7FFF) == 0;
    }
    *flag = (cnt >= 56) ? 1u : 0u;   // 1 = bf16, 0 = fp32
  }
}

__device__ __forceinline__ float cvt(const void* p, size_t i, bool bf) {
  return bf ? (float)((const bf16*)p)[i] : ((const float*)p)[i];
}

// ---------------- weight normalization ---------------------------------------
#define NWTOT 5605888
__global__ __launch_bounds__(256)
void k_conv_w(RawIn R) {
  const bool bf = (*R.flag) != 0;
  for (size_t i = blockIdx.x*256 + threadIdx.x; i < NWTOT; i += (size_t)gridDim.x*256) {
    if (i < 5242880) {           // Ucat [20][512][512]
      size_t g = i >> 18, r = i & 262143;
      const void* s = g<4 ? (g==0?R.U_i:g==1?R.U_f:g==2?R.U_c:R.U_o)
                    : g<12 ? R.U_ix : R.U_cx;
      size_t off = g<4 ? r : g<12 ? (g-4)*262144 + r : (g-12)*262144 + r;
      R.Ucat[i] = cvt(s, off, bf);
    } else {
      size_t j = i - 5242880;
      if (j < 262144) { R.Wa[j] = cvt(R.W_a, j, bf); }
      else {
        size_t j2 = j - 262144;
        if (j2 < 65536) {        // Wm [4][32][512]
          size_t g = j2 >> 14, r = j2 & 16383;
          const void* s = g==0?R.W_i:g==1?R.W_f:g==2?R.W_c:R.W_o;
          R.Wm[j2] = cvt(s, r, bf);
        } else {
          size_t j3 = j2 - 65536;
          if (j3 < 24576) {      // Wx [16][3][512]
            size_t p = j3 / 1536, r = j3 % 1536;
            R.Wx[j3] = p < 8 ? cvt(R.W_ix, p*1536 + r, bf)
                             : cvt(R.W_cx, (p-8)*1536 + r, bf);
          } else {
            size_t j4 = j3 - 24576;
            if (j4 < 2048) {     // Bm [4][512]
              size_t g = j4 >> 9, c = j4 & 511;
              const void* s = g==0?R.b_i:g==1?R.b_f:g==2?R.b_c:R.b_o;
              R.Bm[j4] = cvt(s, c, bf);
            } else {
              size_t j5 = j4 - 2048;
              if (j5 < 8192) {   // Bx [16][512]
                size_t p = j5 >> 9, c = j5 & 511;
                R.Bx[j5] = p < 8 ? cvt(R.b_ix, p*512 + c, bf)
                                 : cvt(R.b_cx, (p-8)*512 + c, bf);
              } else {
                size_t j6 = j5 - 8192;       // Ba [512]
                R.Ba[j6] = cvt(R.b_a, j6, bf);
              }
            }
          }
        }
      }
    }
  }
}

// ---------------- input normalization (time-major pack) -----------------------
#define NYT 2097152
#define NXT 1572864
__global__ __launch_bounds__(256)
void k_conv_in(RawIn R) {
  const bool bf = (*R.flag) != 0;
  for (size_t i = blockIdx.x*256 + threadIdx.x; i < NYT+NXT; i += (size_t)gridDim.x*256) {
    if (i < NYT) {               // Yt [t][b][32]
      size_t j = i & 31, b = (i >> 5) & 63, t = i >> 11;
      R.Yt[i] = cvt(R.Y, (b*32 + j)*NSTEP + t, bf);
    } else {                     // Xt [t][8][b][3]
      size_t i2 = i - NYT;
      size_t j = i2 % 3, r = i2 / 3;
      size_t b = r & 63; r >>= 6;
      size_t a = r & 7, t = r >> 3;
      R.Xt[i2] = cvt(R.x[a], (b*3 + j)*NSTEP + t, bf);
    }
  }
}

// ---------------- helpers -----------------------------------------------------

__device__ __forceinline__ float sigf(float v){ return 1.f/(1.f+expf(-v)); }

__device__ __forceinline__ float gload(const float* p){
  return __hip_atomic_load(p, __ATOMIC_RELAXED, __HIP_MEMORY_SCOPE_AGENT);
}
__device__ __forceinline__ void gstore(float* p, float v){
  __hip_atomic_store(p, v, __ATOMIC_RELAXED, __HIP_MEMORY_SCOPE_AGENT);
}

__device__ __forceinline__ void gbar(unsigned* bar, unsigned bi) {
  __threadfence();
  __syncthreads();
  if (threadIdx.x == 0) {
    __hip_atomic_fetch_add(bar, 1u, __ATOMIC_ACQ_REL, __HIP_MEMORY_SCOPE_AGENT);
    const unsigned target = bi * GRID;
    while (__hip_atomic_load(bar, __ATOMIC_RELAXED, __HIP_MEMORY_SCOPE_AGENT) < target)
      __builtin_amdgcn_s_sleep(1);
  }
  __syncthreads();
  __threadfence();
}

// ---------------- persistent kernel (grid == #CUs) ----------------------------

__global__ __launch_bounds__(NTHR)
void lstm_main(Params P) {
  __shared__ float uB[STRIP][PAD];
  __shared__ float hA[16][PAD];
  __shared__ float yA[16][32];
  __shared__ float xA[8][16][3];
  __shared__ float lB[9][HID+8];
  __shared__ float mp[128][12];

  const bool bfout = (*P.flag) != 0;

  const int w   = blockIdx.x;
  const int tid = threadIdx.x;
  const int bq    = w >> 6;
  const int strip = w & 63;
  const int b0 = bq * 16;
  const int c0 = strip * STRIP;
  const int bgr = tid >> 5;
  const int cgr = tid & 31;
  const int bl  = bgr * 2;
  const int cl  = cgr * 5;
  const int pb  = w >> 2;
  const int ph0 = (w & 3) * 128;
  const int hl  = tid >> 1;
  const int kh  = tid & 1;
  const int hp  = ph0 + hl;

  unsigned bi = 0;

  for (int t = 0; t < NSTEP; ++t) {
    // ===== phase A: z = h @ U_cat (+input proj) -> activations -> Gall =====
    for (int e = tid; e < 16*32; e += NTHR) {
      int b = e >> 5, j = e & 31;
      yA[b][j] = P.Yt[((size_t)t*BATCH + b0 + b)*32 + j];
    }
    for (int e = tid; e < 8*16*3; e += NTHR) {
      int j2 = e % 3; int r = e / 3; int b = r & 15; int a = r >> 4;
      xA[a][b][j2] = P.Xt[(((size_t)t*8 + a)*BATCH + b0 + b)*3 + j2];
    }

    float acc[2][5];
#pragma unroll
    for (int i2=0;i2<2;++i2)
#pragma unroll
      for (int j=0;j<5;++j) acc[i2][j]=0.f;

    for (int kc = 0; kc < HID; kc += KC) {
      __syncthreads();
      for (int e = tid; e < 16*KC; e += NTHR) {
        int b = e >> 5, k = e & 31;
        hA[b][k] = gload(&P.Hg[(size_t)(b0 + b)*HID + kc + k]);
      }
      for (int e = tid; e < STRIP*KC; e += NTHR) {
        int k = e / STRIP, c = e - k*STRIP;
        int cg = c0 + c, g = cg >> 9, cc = cg & 511;
        uB[c][k] = P.Ucat[((size_t)g*HID + (kc + k))*HID + cc];
      }
      __syncthreads();
#pragma unroll 4
      for (int k = 0; k < KC; k += 2) {
        float2 h0 = *(const float2*)&hA[bl  ][k];
        float2 h1 = *(const float2*)&hA[bl+1][k];
#pragma unroll
        for (int j = 0; j < 5; ++j) {
          float2 u = *(const float2*)&uB[cl+j][k];
          acc[0][j] += h0.x*u.x; acc[0][j] += h0.y*u.y;
          acc[1][j] += h1.x*u.x; acc[1][j] += h1.y*u.y;
        }
      }
    }

#pragma unroll
    for (int i2 = 0; i2 < 2; ++i2) {
      int b = b0 + bl + i2;
#pragma unroll
      for (int j = 0; j < 5; ++j) {
        int cg = c0 + cl + j, g = cg >> 9, cc = cg & 511;
        float v = acc[i2][j];
        if (g < 4) {
          float s = P.Bm[g*HID + cc];
          for (int jj = 0; jj < 32; ++jj)
            s += yA[bl+i2][jj] * P.Wm[((size_t)g*32 + jj)*HID + cc];
          v += s;
          v = (g==2) ? tanhf(v) : sigf(v);
        } else if (g < 12) {
          int p = g-4; int a = (p==0) ? 0 : 1;   // ref quirk: i_x 2..8 all read x2
          float s = P.Bx[p*HID + cc];
          for (int jj = 0; jj < 3; ++jj)
            s += xA[a][bl+i2][jj] * P.Wx[((size_t)p*3 + jj)*HID + cc];
          v = sigf(v + s);
        } else {
          int p = g-12;
          float s = P.Bx[(8+p)*HID + cc];
          for (int jj = 0; jj < 3; ++jj)
            s += xA[p][bl+i2][jj] * P.Wx[((size_t)(8+p)*3 + jj)*HID + cc];
          v = tanhf(v + s);
        }
        gstore(&P.Gall[((size_t)g*BATCH + b)*HID + cc], v);
      }
    }

    gbar(P.bar, ++bi);

    // ===== phase B: m = l_all @ W_a, softmax mix, state update =====
    for (int e = tid; e < 9*HID; e += NTHR) {
      int j = e >> 9, h = e & 511;
      float l;
      if (j == 0)
        l = gload(&P.Gall[((size_t)0*BATCH+pb)*HID+h]) *
            gload(&P.Gall[((size_t)2*BATCH+pb)*HID+h]);
      else {
        int p = j-1;
        l = gload(&P.Gall[((size_t)(4+p)*BATCH+pb)*HID+h]) *
            gload(&P.Gall[((size_t)(12+p)*BATCH+pb)*HID+h]);
      }
      lB[j][h] = l;
    }
    __syncthreads();

    float a9[9];
#pragma unroll
    for (int j=0;j<9;++j) a9[j]=0.f;
    {
      const int k0 = kh*256;
      const float* wa = P.Wa + (size_t)k0*HID + hp;
#pragma unroll 2
      for (int k = 0; k < 256; k += 4) {
        float w0 = wa[(size_t)(k+0)*HID];
        float w1 = wa[(size_t)(k+1)*HID];
        float w2 = wa[(size_t)(k+2)*HID];
        float w3 = wa[(size_t)(k+3)*HID];
#pragma unroll
        for (int j=0;j<9;++j) {
          float4 l4 = *(const float4*)&lB[j][k0+k];
          a9[j] += l4.x*w0; a9[j] += l4.y*w1; a9[j] += l4.z*w2; a9[j] += l4.w*w3;
        }
      }
    }
    if (kh) {
#pragma unroll
      for (int j=0;j<9;++j) mp[hl][j] = a9[j];
    }
    __syncthreads();
    if (!kh) {
      float co = P.Cg[(size_t)pb*HID + hp];
      float ba = P.Ba[hp];
      float u9[9], mx = -1e30f;
#pragma unroll
      for (int j=0;j<9;++j) {
        float m = a9[j] + mp[hl][j];
        u9[j] = tanhf(m*co + ba);
        mx = fmaxf(mx, u9[j]);
      }
      float ssum = 0.f, L = 0.f;
#pragma unroll
      for (int j=0;j<9;++j) {
        float e2 = expf(u9[j]-mx);
        ssum += e2;
        L += e2 * lB[j][hp];
      }
      L /= ssum;
      float f = gload(&P.Gall[((size_t)1*BATCH+pb)*HID + hp]);
      float o = gload(&P.Gall[((size_t)3*BATCH+pb)*HID + hp]);
      float cn = f*co + L;
      float hn = o*tanhf(cn);
      P.Cg[(size_t)pb*HID + hp] = cn;
      gstore(&P.Hg[(size_t)pb*HID + hp], hn);
      size_t iseq = (size_t)BATCH*HID + ((size_t)pb*NSTEP + t)*HID + hp;
      if (bfout) ((bf16*)P.out)[iseq] = __float2bfloat16(hn);
      else       ((float*)P.out)[iseq] = hn;
      if (t == NSTEP-1) {
        size_t ih = (size_t)pb*HID + hp;
        if (bfout) ((bf16*)P.out)[ih] = __float2bfloat16(hn);
        else       ((float*)P.out)[ih] = hn;
      }
    }

    gbar(P.bar, ++bi);
  }
}

// ---------------- host entry --------------------------------------------------

extern "C" void kernel_launch(void* const* d_in, const int* in_sizes, int n_in,
                              void* d_out, int out_size, void* d_ws, size_t ws_size,
                              hipStream_t stream) {
  char* ws = (char*)d_ws;

  RawIn R;
  R.Y = d_in[0];
  for (int i = 0; i < 8; ++i) R.x[i] = d_in[1+i];
  R.W_i=d_in[9];  R.U_i=d_in[10]; R.b_i=d_in[11];
  R.W_f=d_in[12]; R.U_f=d_in[13]; R.b_f=d_in[14];
  R.W_c=d_in[15]; R.U_c=d_in[16]; R.b_c=d_in[17];
  R.W_o=d_in[18]; R.U_o=d_in[19]; R.b_o=d_in[20];
  R.W_ix=d_in[21]; R.U_ix=d_in[22]; R.b_ix=d_in[23];
  R.W_cx=d_in[24]; R.U_cx=d_in[25]; R.b_cx=d_in[26];
  R.W_a =d_in[27]; R.b_a =d_in[28];
  R.Ucat=(float*)(ws+OFF_UCAT); R.Wa=(float*)(ws+OFF_WA);
  R.Wm=(float*)(ws+OFF_WM); R.Wx=(float*)(ws+OFF_WX);
  R.Bm=(float*)(ws+OFF_BM); R.Bx=(float*)(ws+OFF_BX); R.Ba=(float*)(ws+OFF_BA);
  R.Yt=(float*)(ws+OFF_YT); R.Xt=(float*)(ws+OFF_XT);
  R.flag=(const unsigned*)(ws+OFF_FLAG);

  Params P;
  P.Ucat=R.Ucat; P.Wa=R.Wa; P.Wm=R.Wm; P.Wx=R.Wx;
  P.Bm=R.Bm; P.Bx=R.Bx; P.Ba=R.Ba; P.Yt=R.Yt; P.Xt=R.Xt;
  P.Hg=(float*)(ws+OFF_HG); P.Cg=(float*)(ws+OFF_CG); P.Gall=(float*)(ws+OFF_GALL);
  P.bar=(unsigned*)(ws+OFF_BAR);
  P.flag=R.flag;
  P.out=d_out;

  // zero barrier/flag + Hg + Cg
  hipMemsetAsync(d_ws, 0, OFF_GALL, stream);

  k_detect<<<1, 64, 0, stream>>>((const unsigned short*)d_in[10], (unsigned*)(ws+OFF_FLAG));
  k_conv_w <<<21899, 256, 0, stream>>>(R);
  k_conv_in<<<14336, 256, 0, stream>>>(R);
  lstm_main<<<dim3(GRID), dim3(NTHR), 0, stream>>>(P);
}

// Round 4
// 191434.265 us; speedup vs baseline: 1.2215x; 1.2215x over previous
//
#include <hip/hip_runtime.h>
#include <hip/hip_bf16.h>

typedef __hip_bfloat16 bf16;

#define NSTEP 1024
#define BATCH 64
#define HID   512
#define GRID  256
#define NTHR  256
#define KC    64      // k-chunk per ks-half staged per iteration

// ---- workspace layout (bytes) ----
#define OFF_BAR   0u
#define OFF_FLAG  64u
#define OFF_HG    256u
#define OFF_CG    131328u
#define OFF_GALL  262400u
#define OFF_UCAT  2883840u
#define OFF_WA    23855360u
#define OFF_WM    24903936u
#define OFF_WX    25166080u
#define OFF_BM    25362688u
#define OFF_BX    25370880u
#define OFF_BA    25403648u
#define OFF_YT    25405696u
#define OFF_XT    33794304u

// ---- LDS carve (float indices), total 36864 floats = 144 KB ----
// persistent: Us[40][516], WmL[40][36], hA[2][64][66]
// overlay A : yA[64][33], xA[8][64][3], red[128][21]
// overlay B : lB[9][520], mp[128][12]
#define L_US    0
#define L_WML   20640
#define L_HA    22080
#define L_YA    30528
#define L_XA    32640
#define L_RED   34176
#define L_LB    30528
#define L_MP    35208
#define L_TOT   36864

#define US(c,k)    smem[L_US  + (c)*516 + (k)]
#define WML(c,j)   smem[L_WML + (c)*36  + (j)]
#define HA(s,b,k)  smem[L_HA  + (s)*4224 + (b)*66 + (k)]
#define YA(b,j)    smem[L_YA  + (b)*33 + (j)]
#define XA(a,b,j)  smem[L_XA  + ((a)*64 + (b))*3 + (j)]
#define RED(q,j)   smem[L_RED + (q)*21 + (j)]
#define LB(j,h)    smem[L_LB  + (j)*520 + (h)]
#define MP(q,j)    smem[L_MP  + (q)*12 + (j)]

struct RawIn {
  const void *Y, *x[8];
  const void *W_i,*U_i,*b_i, *W_f,*U_f,*b_f, *W_c,*U_c,*b_c, *W_o,*U_o,*b_o;
  const void *W_ix,*U_ix,*b_ix, *W_cx,*U_cx,*b_cx, *W_a,*b_a;
  float *Ucat,*Wa,*Wm,*Wx,*Bm,*Bx,*Ba,*Yt,*Xt;
  const unsigned *flag;
};

struct Params {
  const float *Ucat,*Wa,*Wm,*Wx,*Bm,*Bx,*Ba,*Yt,*Xt;
  float *Hg,*Cg,*Gall;
  unsigned *bar;
  const unsigned *flag;
  void *out;
};

// ---------------- dtype probe -------------------------------------------------
__global__ void k_detect(const unsigned short* __restrict__ p, unsigned* flag) {
  if (blockIdx.x == 0 && threadIdx.x == 0) {
    int cnt = 0;
    for (int i = 0; i < 64; ++i) {
      unsigned e = (p[i] >> 7) & 0xFF;
      cnt += (e >= 0x60 && e <= 0x7C) || (p[i] & 0x7FFF) == 0;
    }
    *flag = (cnt >= 56) ? 1u : 0u;   // 1 = bf16, 0 = fp32
  }
}

__device__ __forceinline__ float cvt(const void* p, size_t i, bool bf) {
  return bf ? (float)((const bf16*)p)[i] : ((const float*)p)[i];
}

// ---------------- weight normalization ---------------------------------------
#define NWTOT 5605888
__global__ __launch_bounds__(256)
void k_conv_w(RawIn R) {
  const bool bf = (*R.flag) != 0;
  for (size_t i = blockIdx.x*256 + threadIdx.x; i < NWTOT; i += (size_t)gridDim.x*256) {
    if (i < 5242880) {           // Ucat [20][512][512]
      size_t g = i >> 18, r = i & 262143;
      const void* s = g<4 ? (g==0?R.U_i:g==1?R.U_f:g==2?R.U_c:R.U_o)
                    : g<12 ? R.U_ix : R.U_cx;
      size_t off = g<4 ? r : g<12 ? (g-4)*262144 + r : (g-12)*262144 + r;
      R.Ucat[i] = cvt(s, off, bf);
    } else {
      size_t j = i - 5242880;
      if (j < 262144) { R.Wa[j] = cvt(R.W_a, j, bf); }
      else {
        size_t j2 = j - 262144;
        if (j2 < 65536) {        // Wm [4][32][512]
          size_t g = j2 >> 14, r = j2 & 16383;
          const void* s = g==0?R.W_i:g==1?R.W_f:g==2?R.W_c:R.W_o;
          R.Wm[j2] = cvt(s, r, bf);
        } else {
          size_t j3 = j2 - 65536;
          if (j3 < 24576) {      // Wx [16][3][512]
            size_t p = j3 / 1536, r = j3 % 1536;
            R.Wx[j3] = p < 8 ? cvt(R.W_ix, p*1536 + r, bf)
                             : cvt(R.W_cx, (p-8)*1536 + r, bf);
          } else {
            size_t j4 = j3 - 24576;
            if (j4 < 2048) {     // Bm [4][512]
              size_t g = j4 >> 9, c = j4 & 511;
              const void* s = g==0?R.b_i:g==1?R.b_f:g==2?R.b_c:R.b_o;
              R.Bm[j4] = cvt(s, c, bf);
            } else {
              size_t j5 = j4 - 2048;
              if (j5 < 8192) {   // Bx [16][512]
                size_t p = j5 >> 9, c = j5 & 511;
                R.Bx[j5] = p < 8 ? cvt(R.b_ix, p*512 + c, bf)
                                 : cvt(R.b_cx, (p-8)*512 + c, bf);
              } else {
                size_t j6 = j5 - 8192;       // Ba [512]
                R.Ba[j6] = cvt(R.b_a, j6, bf);
              }
            }
          }
        }
      }
    }
  }
}

// ---------------- input normalization (time-major pack) -----------------------
#define NYT 2097152
#define NXT 1572864
__global__ __launch_bounds__(256)
void k_conv_in(RawIn R) {
  const bool bf = (*R.flag) != 0;
  for (size_t i = blockIdx.x*256 + threadIdx.x; i < NYT+NXT; i += (size_t)gridDim.x*256) {
    if (i < NYT) {               // Yt [t][b][32]
      size_t j = i & 31, b = (i >> 5) & 63, t = i >> 11;
      R.Yt[i] = cvt(R.Y, (b*32 + j)*NSTEP + t, bf);
    } else {                     // Xt [t][8][b][3]
      size_t i2 = i - NYT;
      size_t j = i2 % 3, r = i2 / 3;
      size_t b = r & 63; r >>= 6;
      size_t a = r & 7, t = r >> 3;
      R.Xt[i2] = cvt(R.x[a], (b*3 + j)*NSTEP + t, bf);
    }
  }
}

// ---------------- helpers -----------------------------------------------------

__device__ __forceinline__ float sigf(float v){ return 1.f/(1.f+expf(-v)); }

__device__ __forceinline__ float gload(const float* p){
  return __hip_atomic_load(p, __ATOMIC_RELAXED, __HIP_MEMORY_SCOPE_AGENT);
}
__device__ __forceinline__ void gstore(float* p, float v){
  __hip_atomic_store(p, v, __ATOMIC_RELAXED, __HIP_MEMORY_SCOPE_AGENT);
}

__device__ __forceinline__ void gbar(unsigned* bar, unsigned bi) {
  __threadfence();
  __syncthreads();
  if (threadIdx.x == 0) {
    __hip_atomic_fetch_add(bar, 1u, __ATOMIC_ACQ_REL, __HIP_MEMORY_SCOPE_AGENT);
    const unsigned target = bi * GRID;
    while (__hip_atomic_load(bar, __ATOMIC_RELAXED, __HIP_MEMORY_SCOPE_AGENT) < target)
      __builtin_amdgcn_s_sleep(1);
  }
  __syncthreads();
  __threadfence();
}

// ---------------- persistent kernel (grid == #CUs) ----------------------------

__global__ __launch_bounds__(NTHR)
void lstm_main(Params P) {
  extern __shared__ float smem[];

  const bool bfout = (*P.flag) != 0;

  const int w   = blockIdx.x;
  const int tid = threadIdx.x;
  // phase A: WG owns 40 unique columns, all 64 rows.
  const int c0  = w * 40;
  const int cgr = tid & 7;          // 8 col groups x 5 cols
  const int rgr = (tid >> 3) & 15;  // 16 row groups; rows rgr + 16*i
  const int ksl = tid >> 7;         // k-split half (0: k<256, 1: k>=256)
  const int cl  = cgr * 5;
  // phase B mapping (unchanged from R3): 64 b x 4 h'-quarters
  const int pb  = w >> 2;
  const int ph0 = (w & 3) * 128;
  const int hl  = tid >> 1;
  const int kh  = tid & 1;
  const int hp  = ph0 + hl;

  // ---- one-time init: U strip + per-column input-proj weights into LDS ----
  for (int e = tid; e < 40*512; e += NTHR) {
    int c = e >> 9, k = e & 511;
    int cg = c0 + c, g = cg >> 9, cc = cg & 511;
    US(c, k) = P.Ucat[((size_t)g*HID + k)*HID + cc];
  }
  for (int e = tid; e < 40*33; e += NTHR) {
    int c = e / 33, jj = e % 33;
    int cg = c0 + c, g = cg >> 9, cc = cg & 511;
    float v;
    if (jj == 32) {            // bias slot
      v = g < 4  ? P.Bm[g*HID + cc]
        : g < 12 ? P.Bx[(g-4)*HID + cc]
                 : P.Bx[(8 + g-12)*HID + cc];
    } else if (g < 4) {
      v = P.Wm[((size_t)g*32 + jj)*HID + cc];
    } else if (jj < 3) {
      int p = (g < 12) ? (g-4) : (8 + g-12);
      v = P.Wx[((size_t)p*3 + jj)*HID + cc];
    } else v = 0.f;
    WML(c, jj) = v;
  }
  __syncthreads();

  unsigned bi = 0;

  for (int t = 0; t < NSTEP; ++t) {
    // ===== phase A: z[64][40] = h @ Us (+input proj) -> Gall =====
    for (int e = tid; e < 64*32; e += NTHR) {
      int b = e >> 5, j = e & 31;
      YA(b, j) = P.Yt[((size_t)t*BATCH + b)*32 + j];
    }
    for (int e = tid; e < 8*64*3; e += NTHR) {
      int j2 = e % 3; int r = e / 3; int b = r & 63; int a = r >> 6;
      XA(a, b, j2) = P.Xt[(((size_t)t*8 + a)*BATCH + b)*3 + j2];
    }

    float acc[4][5];
#pragma unroll
    for (int i=0;i<4;++i)
#pragma unroll
      for (int j=0;j<5;++j) acc[i][j]=0.f;

    for (int kc = 0; kc < 256; kc += KC) {
      __syncthreads();
      for (int e = tid; e < 2*64*KC; e += NTHR) {      // 8192 -> 32/thread
        int s2 = e >> 12, b = (e >> 6) & 63, k = e & 63;
        HA(s2, b, k) = gload(&P.Hg[(size_t)b*HID + s2*256 + kc + k]);
      }
      __syncthreads();
      const int kb = ksl*256 + kc;
#pragma unroll 4
      for (int kk = 0; kk < KC; kk += 2) {
        float2 h0 = *(const float2*)&HA(ksl, rgr,      kk);
        float2 h1 = *(const float2*)&HA(ksl, rgr+16,   kk);
        float2 h2 = *(const float2*)&HA(ksl, rgr+32,   kk);
        float2 h3 = *(const float2*)&HA(ksl, rgr+48,   kk);
#pragma unroll
        for (int j = 0; j < 5; ++j) {
          float2 u = *(const float2*)&US(cl+j, kb+kk);
          acc[0][j] += h0.x*u.x; acc[0][j] += h0.y*u.y;
          acc[1][j] += h1.x*u.x; acc[1][j] += h1.y*u.y;
          acc[2][j] += h2.x*u.x; acc[2][j] += h2.y*u.y;
          acc[3][j] += h3.x*u.x; acc[3][j] += h3.y*u.y;
        }
      }
    }

    // k-split reduction: ks=1 threads hand partials to ks=0 partner
    if (ksl) {
      int q = tid - 128;
#pragma unroll
      for (int i=0;i<4;++i)
#pragma unroll
        for (int j=0;j<5;++j) RED(q, i*5+j) = acc[i][j];
    }
    __syncthreads();
    if (!ksl) {
#pragma unroll
      for (int i=0;i<4;++i)
#pragma unroll
        for (int j=0;j<5;++j) acc[i][j] += RED(tid, i*5+j);

      // epilogue: input projection + bias + nonlinearity -> Gall
#pragma unroll
      for (int i = 0; i < 4; ++i) {
        int row = rgr + 16*i;
#pragma unroll
        for (int j = 0; j < 5; ++j) {
          int c = cl + j, cg = c0 + c, g = cg >> 9, cc = cg & 511;
          float v = acc[i][j];
          float s = WML(c, 32);
          if (g < 4) {
            for (int jj = 0; jj < 32; ++jj)
              s += YA(row, jj) * WML(c, jj);
            v += s;
            v = (g==2) ? tanhf(v) : sigf(v);
          } else if (g < 12) {
            int p = g-4; int a = (p==0) ? 0 : 1;  // ref quirk: i_x 2..8 all read x2
            for (int jj = 0; jj < 3; ++jj)
              s += XA(a, row, jj) * WML(c, jj);
            v = sigf(v + s);
          } else {
            int p = g-12;
            for (int jj = 0; jj < 3; ++jj)
              s += XA(p, row, jj) * WML(c, jj);
            v = tanhf(v + s);
          }
          gstore(&P.Gall[((size_t)g*BATCH + row)*HID + cc], v);
        }
      }
    }

    gbar(P.bar, ++bi);

    // ===== phase B: m = l_all @ W_a, softmax mix, state update =====
    for (int e = tid; e < 9*HID; e += NTHR) {
      int j = e >> 9, h = e & 511;
      float l;
      if (j == 0)
        l = gload(&P.Gall[((size_t)0*BATCH+pb)*HID+h]) *
            gload(&P.Gall[((size_t)2*BATCH+pb)*HID+h]);
      else {
        int p = j-1;
        l = gload(&P.Gall[((size_t)(4+p)*BATCH+pb)*HID+h]) *
            gload(&P.Gall[((size_t)(12+p)*BATCH+pb)*HID+h]);
      }
      LB(j, h) = l;
    }
    __syncthreads();

    float a9[9];
#pragma unroll
    for (int j=0;j<9;++j) a9[j]=0.f;
    {
      const int k0 = kh*256;
      const float* wa = P.Wa + (size_t)k0*HID + hp;
#pragma unroll 2
      for (int k = 0; k < 256; k += 4) {
        float w0 = wa[(size_t)(k+0)*HID];
        float w1 = wa[(size_t)(k+1)*HID];
        float w2 = wa[(size_t)(k+2)*HID];
        float w3 = wa[(size_t)(k+3)*HID];
#pragma unroll
        for (int j=0;j<9;++j) {
          float4 l4 = *(const float4*)&LB(j, k0+k);
          a9[j] += l4.x*w0; a9[j] += l4.y*w1; a9[j] += l4.z*w2; a9[j] += l4.w*w3;
        }
      }
    }
    if (kh) {
#pragma unroll
      for (int j=0;j<9;++j) MP(hl, j) = a9[j];
    }
    __syncthreads();
    if (!kh) {
      float co = P.Cg[(size_t)pb*HID + hp];
      float ba = P.Ba[hp];
      float u9[9], mx = -1e30f;
#pragma unroll
      for (int j=0;j<9;++j) {
        float m = a9[j] + MP(hl, j);
        u9[j] = tanhf(m*co + ba);
        mx = fmaxf(mx, u9[j]);
      }
      float ssum = 0.f, L = 0.f;
#pragma unroll
      for (int j=0;j<9;++j) {
        float e2 = expf(u9[j]-mx);
        ssum += e2;
        L += e2 * LB(j, hp);
      }
      L /= ssum;
      float f = gload(&P.Gall[((size_t)1*BATCH+pb)*HID + hp]);
      float o = gload(&P.Gall[((size_t)3*BATCH+pb)*HID + hp]);
      float cn = f*co + L;
      float hn = o*tanhf(cn);
      P.Cg[(size_t)pb*HID + hp] = cn;
      gstore(&P.Hg[(size_t)pb*HID + hp], hn);
      size_t iseq = (size_t)BATCH*HID + ((size_t)pb*NSTEP + t)*HID + hp;
      if (bfout) ((bf16*)P.out)[iseq] = __float2bfloat16(hn);
      else       ((float*)P.out)[iseq] = hn;
      if (t == NSTEP-1) {
        size_t ih = (size_t)pb*HID + hp;
        if (bfout) ((bf16*)P.out)[ih] = __float2bfloat16(hn);
        else       ((float*)P.out)[ih] = hn;
      }
    }

    gbar(P.bar, ++bi);
  }
}

// ---------------- host entry --------------------------------------------------

extern "C" void kernel_launch(void* const* d_in, const int* in_sizes, int n_in,
                              void* d_out, int out_size, void* d_ws, size_t ws_size,
                              hipStream_t stream) {
  char* ws = (char*)d_ws;

  RawIn R;
  R.Y = d_in[0];
  for (int i = 0; i < 8; ++i) R.x[i] = d_in[1+i];
  R.W_i=d_in[9];  R.U_i=d_in[10]; R.b_i=d_in[11];
  R.W_f=d_in[12]; R.U_f=d_in[13]; R.b_f=d_in[14];
  R.W_c=d_in[15]; R.U_c=d_in[16]; R.b_c=d_in[17];
  R.W_o=d_in[18]; R.U_o=d_in[19]; R.b_o=d_in[20];
  R.W_ix=d_in[21]; R.U_ix=d_in[22]; R.b_ix=d_in[23];
  R.W_cx=d_in[24]; R.U_cx=d_in[25]; R.b_cx=d_in[26];
  R.W_a =d_in[27]; R.b_a =d_in[28];
  R.Ucat=(float*)(ws+OFF_UCAT); R.Wa=(float*)(ws+OFF_WA);
  R.Wm=(float*)(ws+OFF_WM); R.Wx=(float*)(ws+OFF_WX);
  R.Bm=(float*)(ws+OFF_BM); R.Bx=(float*)(ws+OFF_BX); R.Ba=(float*)(ws+OFF_BA);
  R.Yt=(float*)(ws+OFF_YT); R.Xt=(float*)(ws+OFF_XT);
  R.flag=(const unsigned*)(ws+OFF_FLAG);

  Params P;
  P.Ucat=R.Ucat; P.Wa=R.Wa; P.Wm=R.Wm; P.Wx=R.Wx;
  P.Bm=R.Bm; P.Bx=R.Bx; P.Ba=R.Ba; P.Yt=R.Yt; P.Xt=R.Xt;
  P.Hg=(float*)(ws+OFF_HG); P.Cg=(float*)(ws+OFF_CG); P.Gall=(float*)(ws+OFF_GALL);
  P.bar=(unsigned*)(ws+OFF_BAR);
  P.flag=R.flag;
  P.out=d_out;

  // zero barrier/flag + Hg + Cg (ws is poisoned 0xAA before every call)
  hipMemsetAsync(d_ws, 0, OFF_GALL, stream);

  k_detect<<<1, 64, 0, stream>>>((const unsigned short*)d_in[10], (unsigned*)(ws+OFF_FLAG));
  k_conv_w <<<21899, 256, 0, stream>>>(R);
  k_conv_in<<<14336, 256, 0, stream>>>(R);

  const int smemBytes = L_TOT * 4;   // 147456 B = 144 KB (<160 KB/CU, 1 WG/CU)
  hipFuncSetAttribute((const void*)lstm_main,
                      hipFuncAttributeMaxDynamicSharedMemorySize, smemBytes);
  lstm_main<<<dim3(GRID), dim3(NTHR), smemBytes, stream>>>(P);
}